// Round 3
// baseline (676.063 us; speedup 1.0000x reference)
//
#include <hip/hip_runtime.h>

// GRU (B=4096, T=2048, H=8, I=4) + fused FC (O=4), fp32.
// R5: TLP fix. R4 measured 395 cyc/step with ~72 inst/step (~184 issue cyc)
// and chain depth 13 (~90-130 cyc latency): wall = issue + EXPOSED stalls,
// because 1024 waves = exactly 1 wave/SIMD -> nothing fills dependency
// stalls. This version duplicates the 16-lane element pattern across TWO
// DPP rows (32 lanes/elem, lanes q and q+16 identical) -> 2048 waves =
// 2/SIMD, so the sibling wave fills the stall windows. Redundant compute
// doubles (irrelevant, far from FLOP roofline); stores are row-predicated:
// row 0 flushes step-groups =0-3 (mod 8), row 1 flushes =4-7 (mod 8) incl.
// the epilogue, keeping WRITE_SIZE at exactly the output size.
//
// Carried from R4 (all verified):
//  - row_ror:1..7 depth-1 gather of duplicated h (weights pre-permuted by
//    (m-r)&7); r-gate as 4-leaf fma tree; sigmoid/tanh scale constants
//    folded into weights; update as hn = fma(-2*omz, u, fma(omz, 1-h, h));
//    FC lagged one step reusing the gather; ping-pong x prefetch.

#define GRU_T 2048
#define GRU_H 8
#define GRU_I 4
#define GRU_O 4
#define PFD   8        // per ping-pong half; 2*PFD must divide T

#define DPP_ROR(n) (0x120 + (n))   // row_ror:n : lane i <- lane (i-n)&15

template <int CTRL>
__device__ __forceinline__ float dpp_movf(float v) {
    return __int_as_float(
        __builtin_amdgcn_mov_dpp(__float_as_int(v), CTRL, 0xf, 0xf, true));
}

__device__ __forceinline__ float fast_rcp(float x)  { return __builtin_amdgcn_rcpf(x); }
__device__ __forceinline__ float fast_exp2(float x) { return __builtin_amdgcn_exp2f(x); }

__global__ __launch_bounds__(64, 1) void gru_fc_kernel(
    const float* __restrict__ x,
    const float* __restrict__ W_ih,
    const float* __restrict__ W_hh,
    const float* __restrict__ b_ih,
    const float* __restrict__ b_hh,
    const float* __restrict__ W_fc,
    const float* __restrict__ b_fc,
    float* __restrict__ out)
{
    const int tid = blockIdx.x * 64 + (int)threadIdx.x;
    const int b   = tid >> 5;            // batch element (2 per wave)
    const int row = (tid >> 4) & 1;      // duplicate row within the element
    const int q   = tid & 15;            // lane within the 16-lane row
    const int m   = q & 7;               // hidden index this lane owns
    const int o   = q & 3;               // FC output index (duplicated)

    // scale folding: sigma(a) = rcp(1+exp2(SR*a)); 1-sigma(a) =
    // rcp(1+exp2(SZ*a)); tanh(y) = 1 - 2*rcp(1+exp2(SN*y))
    const float SR = -1.4426950408889634f;
    const float SZ =  1.4426950408889634f;
    const float SN =  2.8853900817779268f;

    float whr[8], whz[8], whn[8], wf[8];
#pragma unroll
    for (int r = 0; r < 8; ++r) {
        const int k = (m - r) & 7;       // rot[r] holds h[(m-r)&7]
        whr[r] = SR * W_hh[(0 * GRU_H + m) * GRU_H + k];
        whz[r] = SZ * W_hh[(1 * GRU_H + m) * GRU_H + k];
        whn[r] = SN * W_hh[(2 * GRU_H + m) * GRU_H + k];
        wf[r]  = W_fc[o * GRU_H + k];
    }
    float wir[4], wiz[4], win[4];
#pragma unroll
    for (int k = 0; k < 4; ++k) {
        wir[k] = SR * W_ih[(0 * GRU_H + m) * GRU_I + k];
        wiz[k] = SZ * W_ih[(1 * GRU_H + m) * GRU_I + k];
        win[k] = SN * W_ih[(2 * GRU_H + m) * GRU_I + k];
    }
    const float br  = SR * (b_ih[m] + b_hh[m]);
    const float bz  = SZ * (b_ih[GRU_H + m] + b_hh[GRU_H + m]);
    const float bxn = SN * b_ih[2 * GRU_H + m];
    const float bhn = SN * b_hh[2 * GRU_H + m];
    const float bo  = b_fc[o];

    float hprev = 0.0f;
    float bank0 = 0.0f, bank1 = 0.0f, bank2 = 0.0f;

    const float4* __restrict__ xp = reinterpret_cast<const float4*>(x) + (size_t)b * GRU_T;
    float* __restrict__ op = out + (size_t)b * GRU_T * GRU_O + q;

    float4 bufA[PFD], bufB[PFD];
#pragma unroll
    for (int j = 0; j < PFD; ++j) bufA[j] = xp[j];

// flush wanted by row ((JM>>2)&1)^1: JM=0 stores steps =4-7 (mod 8) -> row 1,
// JM=4 stores steps =0-3 (mod 8) -> row 0.
#define GRU_STEP(XC, TCUR, JM)                                                 \
    do {                                                                       \
        const float4 xc = (XC);                                                \
        /* x-parts + helpers: independent of h, fill stall shadows */          \
        const float xrA = fmaf(wir[1], xc.y, fmaf(wir[0], xc.x, br));          \
        const float xrB = fmaf(wir[3], xc.w, wir[2] * xc.z);                   \
        const float xzA = fmaf(wiz[1], xc.y, fmaf(wiz[0], xc.x, bz));          \
        const float xzB = fmaf(wiz[3], xc.w, wiz[2] * xc.z);                   \
        const float xn_ = fmaf(win[3], xc.w, fmaf(win[2], xc.z,                \
                          fmaf(win[1], xc.y, fmaf(win[0], xc.x, bxn))));       \
        const float onemh = 1.0f - hprev;                                      \
        /* depth-1 rotation gather: rk = h_prev[(m-k)&7] */                    \
        const float r1 = dpp_movf<DPP_ROR(1)>(hprev);                          \
        const float r2 = dpp_movf<DPP_ROR(2)>(hprev);                          \
        const float r3 = dpp_movf<DPP_ROR(3)>(hprev);                          \
        const float r4 = dpp_movf<DPP_ROR(4)>(hprev);                          \
        const float r5 = dpp_movf<DPP_ROR(5)>(hprev);                          \
        const float r6 = dpp_movf<DPP_ROR(6)>(hprev);                          \
        const float r7 = dpp_movf<DPP_ROR(7)>(hprev);                          \
        /* r-gate: 4-leaf tree, ar ready at depth 5 (critical path) */         \
        const float tA = fmaf(whr[1], r1, fmaf(whr[0], hprev, xrA));           \
        const float tB = fmaf(whr[3], r3, fmaf(whr[2], r2, xrB));              \
        const float tC = fmaf(whr[5], r5, whr[4] * r4);                        \
        const float tD = fmaf(whr[7], r7, whr[6] * r6);                        \
        const float ar = (tA + tB) + (tC + tD);                                \
        /* z / n-h dots: two 4-chains (off-critical slack) */                  \
        const float zA = fmaf(whz[3], r3, fmaf(whz[2], r2,                     \
                         fmaf(whz[1], r1, fmaf(whz[0], hprev, xzA))));         \
        const float zB = fmaf(whz[7], r7, fmaf(whz[6], r6,                     \
                         fmaf(whz[5], r5, fmaf(whz[4], r4, xzB))));            \
        const float az = zA + zB;                                              \
        const float nA = fmaf(whn[3], r3, fmaf(whn[2], r2,                     \
                         fmaf(whn[1], r1, fmaf(whn[0], hprev, bhn))));         \
        const float nB = fmaf(whn[7], r7, fmaf(whn[6], r6,                     \
                         fmaf(whn[5], r5, whn[4] * r4)));                      \
        const float ahn = nA + nB;                                             \
        /* lagged FC on h(t-1), reusing the rotation gather */                 \
        const float fA = fmaf(wf[3], r3, fmaf(wf[2], r2,                       \
                         fmaf(wf[1], r1, fmaf(wf[0], hprev, bo))));            \
        const float fB = fmaf(wf[7], r7, fmaf(wf[6], r6,                       \
                         fmaf(wf[5], r5, wf[4] * r4)));                        \
        const float fc = fA + fB;                                              \
        /* nonlinear tail (cycle: exp add rcp, fma, exp add rcp, fma) */       \
        const float rg  = fast_rcp(1.0f + fast_exp2(ar));                      \
        const float omz = fast_rcp(1.0f + fast_exp2(az));     /* = 1-z */      \
        const float c1  = fmaf(omz, onemh, hprev);                             \
        const float m2z = -2.0f * omz;                                         \
        const float yn  = fmaf(rg, ahn, xn_);                                  \
        const float u   = fast_rcp(1.0f + fast_exp2(yn));                      \
        hprev = fmaf(m2z, u, c1);        /* h + omz*(1-h) - 2*omz*u */         \
        /* bank fc by s=(t-1)&3; row-predicated 16-dword flush per 4 steps */  \
        if (((JM) & 3) == 1)      bank0 = fc;                                  \
        else if (((JM) & 3) == 2) bank1 = fc;                                  \
        else if (((JM) & 3) == 3) bank2 = fc;                                  \
        else if ((TCUR) != 0 && row == ((((JM) >> 2) & 1) ^ 1)) {              \
            const float v01 = (q & 4) ? bank1 : bank0;                         \
            const float v23 = (q & 4) ? fc    : bank2;                         \
            const float val = (q & 8) ? v23   : v01;                           \
            op[(size_t)((TCUR) - 4) * GRU_O] = val;                            \
        }                                                                      \
    } while (0)

    for (int tb = 0; tb < GRU_T; tb += 2 * PFD) {
#pragma unroll
        for (int j = 0; j < PFD; ++j) bufB[j] = xp[tb + PFD + j];
#pragma unroll
        for (int j = 0; j < PFD; ++j) GRU_STEP(bufA[j], tb + j, j);
        const int tn = (tb + 2 * PFD) & (GRU_T - 1);   // wrap; values unused
#pragma unroll
        for (int j = 0; j < PFD; ++j) bufA[j] = xp[tn + j];
#pragma unroll
        for (int j = 0; j < PFD; ++j) GRU_STEP(bufB[j], tb + PFD + j, j);
    }

    // epilogue: flush lagged FC for steps T-4..T-1 (steps =4-7 mod 8 -> row 1)
    if (row == 1) {
        const float r1 = dpp_movf<DPP_ROR(1)>(hprev);
        const float r2 = dpp_movf<DPP_ROR(2)>(hprev);
        const float r3 = dpp_movf<DPP_ROR(3)>(hprev);
        const float r4 = dpp_movf<DPP_ROR(4)>(hprev);
        const float r5 = dpp_movf<DPP_ROR(5)>(hprev);
        const float r6 = dpp_movf<DPP_ROR(6)>(hprev);
        const float r7 = dpp_movf<DPP_ROR(7)>(hprev);
        const float fA = fmaf(wf[3], r3, fmaf(wf[2], r2,
                         fmaf(wf[1], r1, fmaf(wf[0], hprev, bo))));
        const float fB = fmaf(wf[7], r7, fmaf(wf[6], r6,
                         fmaf(wf[5], r5, wf[4] * r4)));
        const float fc = fA + fB;
        const float v01 = (q & 4) ? bank1 : bank0;
        const float v23 = (q & 4) ? fc    : bank2;
        const float val = (q & 8) ? v23   : v01;
        op[(size_t)(GRU_T - 4) * GRU_O] = val;
    }
#undef GRU_STEP
}

extern "C" void kernel_launch(void* const* d_in, const int* in_sizes, int n_in,
                              void* d_out, int out_size, void* d_ws, size_t ws_size,
                              hipStream_t stream) {
    const float* x    = (const float*)d_in[0];
    const float* W_ih = (const float*)d_in[1];
    const float* W_hh = (const float*)d_in[2];
    const float* b_ih = (const float*)d_in[3];
    const float* b_hh = (const float*)d_in[4];
    const float* W_fc = (const float*)d_in[5];
    const float* b_fc = (const float*)d_in[6];
    float* out = (float*)d_out;

    const int B = in_sizes[0] / (GRU_T * GRU_I);   // 4096
    dim3 grid((unsigned)(B * 32 / 64)), block(64); // 32 lanes/elem, 2048 waves
    hipLaunchKernelGGL(gru_fc_kernel, grid, block, 0, stream,
                       x, W_ih, W_hh, b_ih, b_hh, W_fc, b_fc, out);
}

// Round 4
// 422.893 us; speedup vs baseline: 1.5987x; 1.5987x over previous
//
#include <hip/hip_runtime.h>

// GRU (B=4096, T=2048, H=8, I=4) + fused FC (O=4), fp32.
// R6: gate-split lockstep specialization. Model (settled by R2/R4/R5):
// wall/step = per-SIMD issue cycles (~80%) + small tail-chain stall (~20%);
// R5 proved issue saturation (2x duplicated waves -> busy exactly 2x, 571us).
// Only remaining lever: shrink the instruction stream without duplication.
// Lane-pair (m, m+8) previously computed identical work. Now:
//   g=0 lanes accumulate ar (SR-scaled weights), g=1 lanes az (SZ-scaled)
//   over the SAME rotation registers (split by weight contents, which is the
//   only split lockstep allows: an/FC dots can't split because a lane's
//   rotations only cover its own hidden unit and DPP register names are
//   per-instruction). Each lane runs ONE sigmoid: g0 -> r, g1 -> omz=1-z;
//   one ror8 + 2 cndmask distribute both to all lanes. Saves 12 FMA + 2 of
//   6 transcendentals per lane-step (stream ~73 -> ~61), chain 13 -> 14.
// Carried from R4: row_ror:1..7 depth-1 gather (weights pre-permuted by
// (m-r)&7), scale-folded sigmoid/tanh, hn = fma(-2*omz, u, fma(omz,1-h,h)),
// lagged FC reusing the gather, ping-pong x prefetch, banked 16-dword stores.

#define GRU_T 2048
#define GRU_H 8
#define GRU_I 4
#define GRU_O 4
#define PFD   8        // per ping-pong half; 2*PFD must divide T

#define DPP_ROR(n) (0x120 + (n))   // row_ror:n : lane i <- lane (i-n)&15

template <int CTRL>
__device__ __forceinline__ float dpp_movf(float v) {
    return __int_as_float(
        __builtin_amdgcn_mov_dpp(__float_as_int(v), CTRL, 0xf, 0xf, true));
}

__device__ __forceinline__ float fast_rcp(float x)  { return __builtin_amdgcn_rcpf(x); }
__device__ __forceinline__ float fast_exp2(float x) { return __builtin_amdgcn_exp2f(x); }

__global__ __launch_bounds__(64, 1) void gru_fc_kernel(
    const float* __restrict__ x,
    const float* __restrict__ W_ih,
    const float* __restrict__ W_hh,
    const float* __restrict__ b_ih,
    const float* __restrict__ b_hh,
    const float* __restrict__ W_fc,
    const float* __restrict__ b_fc,
    float* __restrict__ out)
{
    const int tid = blockIdx.x * 64 + (int)threadIdx.x;
    const int b   = tid >> 4;            // batch element (4 per wave)
    const int q   = tid & 15;            // lane within element (one DPP row)
    const int g   = (q >> 3) & 1;        // 0: r-gate lane, 1: z-gate lane
    const int m   = q & 7;               // hidden index this lane owns
    const int o   = q & 3;               // FC output index (4x duplicated)
    const bool hi = (q & 8) != 0;

    // scale folding: sigma(a) = rcp(1+exp2(SR*a)); 1-sigma(a) =
    // rcp(1+exp2(SZ*a)); tanh(y) = 1 - 2*rcp(1+exp2(SN*y))
    const float SR = -1.4426950408889634f;
    const float SZ =  1.4426950408889634f;
    const float SN =  2.8853900817779268f;

    const float SG   = g ? SZ : SR;      // own-gate scale
    const int   gate = g ? 1 : 0;        // own-gate row block in W_*h

    float whA[8], whn[8], wf[8];
#pragma unroll
    for (int r = 0; r < 8; ++r) {
        const int k = (m - r) & 7;       // rot[r] holds h[(m-r)&7]
        whA[r] = SG * W_hh[(gate * GRU_H + m) * GRU_H + k];
        whn[r] = SN * W_hh[(2 * GRU_H + m) * GRU_H + k];
        wf[r]  = W_fc[o * GRU_H + k];
    }
    float wiA[4], win[4];
#pragma unroll
    for (int k = 0; k < 4; ++k) {
        wiA[k] = SG * W_ih[(gate * GRU_H + m) * GRU_I + k];
        win[k] = SN * W_ih[(2 * GRU_H + m) * GRU_I + k];
    }
    const float bA  = SG * (b_ih[gate * GRU_H + m] + b_hh[gate * GRU_H + m]);
    const float bxn = SN * b_ih[2 * GRU_H + m];
    const float bhn = SN * b_hh[2 * GRU_H + m];
    const float bo  = b_fc[o];

    float hprev = 0.0f;
    float bank0 = 0.0f, bank1 = 0.0f, bank2 = 0.0f;

    const float4* __restrict__ xp = reinterpret_cast<const float4*>(x) + (size_t)b * GRU_T;
    float* __restrict__ op = out + (size_t)b * GRU_T * GRU_O + q;

    float4 bufA[PFD], bufB[PFD];
#pragma unroll
    for (int j = 0; j < PFD; ++j) bufA[j] = xp[j];

#define GRU_STEP(XC, TCUR, JM)                                                 \
    do {                                                                       \
        const float4 xc = (XC);                                                \
        /* own-gate x-part + n x-part: independent of h, fill shadows */       \
        const float xA  = fmaf(wiA[1], xc.y, fmaf(wiA[0], xc.x, bA));          \
        const float xB  = fmaf(wiA[3], xc.w, wiA[2] * xc.z);                   \
        const float xn_ = fmaf(win[3], xc.w, fmaf(win[2], xc.z,                \
                          fmaf(win[1], xc.y, fmaf(win[0], xc.x, bxn))));       \
        const float onemh = 1.0f - hprev;                                      \
        /* depth-1 rotation gather: rk = h_prev[(m-k)&7] */                    \
        const float r1 = dpp_movf<DPP_ROR(1)>(hprev);                          \
        const float r2 = dpp_movf<DPP_ROR(2)>(hprev);                          \
        const float r3 = dpp_movf<DPP_ROR(3)>(hprev);                          \
        const float r4 = dpp_movf<DPP_ROR(4)>(hprev);                          \
        const float r5 = dpp_movf<DPP_ROR(5)>(hprev);                          \
        const float r6 = dpp_movf<DPP_ROR(6)>(hprev);                          \
        const float r7 = dpp_movf<DPP_ROR(7)>(hprev);                          \
        /* own-gate hh dot: 4-leaf tree (g0 -> ar, g1 -> az) */                \
        const float tA = fmaf(whA[1], r1, fmaf(whA[0], hprev, xA));            \
        const float tB = fmaf(whA[3], r3, fmaf(whA[2], r2, xB));               \
        const float tC = fmaf(whA[5], r5, whA[4] * r4);                        \
        const float tD = fmaf(whA[7], r7, whA[6] * r6);                        \
        const float aOwn = (tA + tB) + (tC + tD);                              \
        /* one sigmoid per lane: g0 -> r, g1 -> omz = 1-z */                   \
        const float sOwn = fast_rcp(1.0f + fast_exp2(aOwn));                   \
        /* exchange results across the pair (lane q <-> q^8) */                \
        const float sSib = dpp_movf<DPP_ROR(8)>(sOwn);                         \
        const float rg   = hi ? sSib : sOwn;                                   \
        const float omz  = hi ? sOwn : sSib;                                   \
        /* n-gate h dot: two 4-chains (slack vs the r path) */                 \
        const float nA = fmaf(whn[3], r3, fmaf(whn[2], r2,                     \
                         fmaf(whn[1], r1, fmaf(whn[0], hprev, bhn))));         \
        const float nB = fmaf(whn[7], r7, fmaf(whn[6], r6,                     \
                         fmaf(whn[5], r5, whn[4] * r4)));                      \
        const float ahn = nA + nB;                                             \
        /* lagged FC on h(t-1), reusing the rotation gather */                 \
        const float fA = fmaf(wf[3], r3, fmaf(wf[2], r2,                       \
                         fmaf(wf[1], r1, fmaf(wf[0], hprev, bo))));            \
        const float fB = fmaf(wf[7], r7, fmaf(wf[6], r6,                       \
                         fmaf(wf[5], r5, wf[4] * r4)));                        \
        const float fc = fA + fB;                                              \
        /* tail: exp add rcp, fma, fma */                                      \
        const float c1  = fmaf(omz, onemh, hprev);                             \
        const float m2z = -2.0f * omz;                                         \
        const float yn  = fmaf(rg, ahn, xn_);                                  \
        const float u   = fast_rcp(1.0f + fast_exp2(yn));                      \
        hprev = fmaf(m2z, u, c1);        /* h + omz*(1-h) - 2*omz*u */         \
        /* bank fc by s=(t-1)&3; store 4 steps per 16-dword chunk */           \
        if (((JM) & 3) == 1)      bank0 = fc;                                  \
        else if (((JM) & 3) == 2) bank1 = fc;                                  \
        else if (((JM) & 3) == 3) bank2 = fc;                                  \
        else if ((TCUR) != 0) {                                                \
            const float v01 = (q & 4) ? bank1 : bank0;                         \
            const float v23 = (q & 4) ? fc    : bank2;                         \
            const float val = (q & 8) ? v23   : v01;                           \
            op[(size_t)((TCUR) - 4) * GRU_O] = val;                            \
        }                                                                      \
    } while (0)

    for (int tb = 0; tb < GRU_T; tb += 2 * PFD) {
#pragma unroll
        for (int j = 0; j < PFD; ++j) bufB[j] = xp[tb + PFD + j];
#pragma unroll
        for (int j = 0; j < PFD; ++j) GRU_STEP(bufA[j], tb + j, j);
        const int tn = (tb + 2 * PFD) & (GRU_T - 1);   // wrap; values unused
#pragma unroll
        for (int j = 0; j < PFD; ++j) bufA[j] = xp[tn + j];
#pragma unroll
        for (int j = 0; j < PFD; ++j) GRU_STEP(bufB[j], tb + PFD + j, j);
    }

    // epilogue: flush lagged FC for step T-1 (h = final hprev)
    {
        const float r1 = dpp_movf<DPP_ROR(1)>(hprev);
        const float r2 = dpp_movf<DPP_ROR(2)>(hprev);
        const float r3 = dpp_movf<DPP_ROR(3)>(hprev);
        const float r4 = dpp_movf<DPP_ROR(4)>(hprev);
        const float r5 = dpp_movf<DPP_ROR(5)>(hprev);
        const float r6 = dpp_movf<DPP_ROR(6)>(hprev);
        const float r7 = dpp_movf<DPP_ROR(7)>(hprev);
        const float fA = fmaf(wf[3], r3, fmaf(wf[2], r2,
                         fmaf(wf[1], r1, fmaf(wf[0], hprev, bo))));
        const float fB = fmaf(wf[7], r7, fmaf(wf[6], r6,
                         fmaf(wf[5], r5, wf[4] * r4)));
        const float fc = fA + fB;
        const float v01 = (q & 4) ? bank1 : bank0;
        const float v23 = (q & 4) ? fc    : bank2;
        const float val = (q & 8) ? v23   : v01;
        op[(size_t)(GRU_T - 4) * GRU_O] = val;
    }
#undef GRU_STEP
}

extern "C" void kernel_launch(void* const* d_in, const int* in_sizes, int n_in,
                              void* d_out, int out_size, void* d_ws, size_t ws_size,
                              hipStream_t stream) {
    const float* x    = (const float*)d_in[0];
    const float* W_ih = (const float*)d_in[1];
    const float* W_hh = (const float*)d_in[2];
    const float* b_ih = (const float*)d_in[3];
    const float* b_hh = (const float*)d_in[4];
    const float* W_fc = (const float*)d_in[5];
    const float* b_fc = (const float*)d_in[6];
    float* out = (float*)d_out;

    const int B = in_sizes[0] / (GRU_T * GRU_I);   // 4096
    dim3 grid((unsigned)(B * 16 / 64)), block(64); // 16 lanes/elem, 1024 waves
    hipLaunchKernelGGL(gru_fc_kernel, grid, block, 0, stream,
                       x, W_ih, W_hh, b_ih, b_hh, W_fc, b_fc, out);
}